// Round 5
// baseline (560.446 us; speedup 1.0000x reference)
//
#include <hip/hip_runtime.h>

#define KDIM 32
#define CAP 160   // slot capacity per atom; counts ~ Poisson(32), P(>=160) ~ 0

// ---------------- slotted CSR build: one memset + one scatter pass ----------
// recs[c*CAP + pos] = (edge_id, neighbor_id), pos = atomicAdd(cursor[c])
__global__ void scatter_slots_kernel(const int* __restrict__ centers,
                                     const int* __restrict__ neighbors,
                                     int* __restrict__ cursor,
                                     int2* __restrict__ recs, int n) {
    int i = blockIdx.x * blockDim.x + threadIdx.x;
    if (i < n) {
        int c  = centers[i];
        int nn = neighbors[i];
        int pos = atomicAdd(&cursor[c], 1);
        if (pos < CAP) recs[(size_t)c * CAP + pos] = make_int2(i, nn);
    }
}

// ---------------- main: one wave per atom, 2-wide lanes ----------------
// lane = h*16 + kk ; h = 0..3 row-group, kk = 0..15 k-pair, k = 2*kk,2*kk+1.
// Lane owns output rows r = 4h+j (j=0..3) at columns k0,k0+1 (8 accumulators).
// l(row): r0->l0, r1..3->l1, r4..8->l2, r9..15->l3, so per h-group:
//   h=0: rows 0..3  -> tA=0 (row0), tB=1 (rows1-3)
//   h=1: rows 4..7  -> tA=tB=2
//   h=2: rows 8..11 -> tA=2 (row8), tB=3 (rows9-11)
//   h=3: rows 12..15-> tA=tB=3
// Row j=0 always uses wA, rows j=1..3 always use wB (uniform, no selects).
// Per-edge vmem: 2x dwordx2 (rb rows tA,tB) + 1x dwordx2 (emb) + 1x float4 (sh)
//   = 4 wide gathers (was 7).  Bytes fetched unchanged.
// recs fetched 8-at-a-time via one lane-distributed load + readlane, with
// one-batch prefetch.

#define EDGE_BODY2(E0, N0)                                                \
    {                                                                     \
        const float2* rpA = (const float2*)(rb + (size_t)(E0) * 128 + tA * 32 + k0); \
        const float2* rpB = (const float2*)(rb + (size_t)(E0) * 128 + tB * 32 + k0); \
        const float2* ep  = (const float2*)(emb + (size_t)(N0) * KDIM + k0);          \
        const float4* sp  = (const float4*)(sh + (size_t)(E0) * 16 + 4 * h);          \
        float2 wA = *rpA;                                                 \
        float2 wB = *rpB;                                                 \
        float2 em = *ep;                                                  \
        float4 s  = *sp;                                                  \
        wA.x *= em.x; wA.y *= em.y;                                       \
        wB.x *= em.x; wB.y *= em.y;                                       \
        a0x += s.x * wA.x; a0y += s.x * wA.y;                             \
        a1x += s.y * wB.x; a1y += s.y * wB.y;                             \
        a2x += s.z * wB.x; a2y += s.z * wB.y;                             \
        a3x += s.w * wB.x; a3y += s.w * wB.y;                             \
    }

#define RL(x, j) __builtin_amdgcn_readlane((x), (j))

__global__ __launch_bounds__(256) void imp_main_kernel(
    const float* __restrict__ sh, const float* __restrict__ rb,
    const float* __restrict__ emb, const int2* __restrict__ recs,
    const int* __restrict__ cursor, float* __restrict__ out, int n_atoms) {
    int wave = (blockIdx.x * blockDim.x + threadIdx.x) >> 6;
    int lane = threadIdx.x & 63;
    if (wave >= n_atoms) return;
    int h  = lane >> 4;   // 0..3
    int kk = lane & 15;   // 0..15
    int k0 = kk * 2;

    int tA = (h == 0) ? 0 : ((h == 3) ? 3 : 2);
    int tB = (h == 0) ? 1 : ((h == 1) ? 2 : 3);

    int cnt = cursor[wave];
    if (cnt > CAP) cnt = CAP;
    const int2* rbase = recs + (size_t)wave * CAP;

    float a0x = 0.f, a0y = 0.f, a1x = 0.f, a1y = 0.f;
    float a2x = 0.f, a2y = 0.f, a3x = 0.f, a3y = 0.f;

    int l8 = lane & 7;
    int i = 0;
    int2 cur = make_int2(0, 0);
    if (cnt >= 8) cur = rbase[l8];          // preload batch 0
    while (i + 8 <= cnt) {
        int2 nxt = cur;
        if (i + 16 <= cnt) nxt = rbase[i + 8 + l8];  // prefetch next batch

        int e0 = RL(cur.x, 0), n0 = RL(cur.y, 0);
        int e1 = RL(cur.x, 1), n1 = RL(cur.y, 1);
        int e2 = RL(cur.x, 2), n2 = RL(cur.y, 2);
        int e3 = RL(cur.x, 3), n3 = RL(cur.y, 3);
        int e4 = RL(cur.x, 4), n4 = RL(cur.y, 4);
        int e5 = RL(cur.x, 5), n5 = RL(cur.y, 5);
        int e6 = RL(cur.x, 6), n6 = RL(cur.y, 6);
        int e7 = RL(cur.x, 7), n7 = RL(cur.y, 7);

        EDGE_BODY2(e0, n0)
        EDGE_BODY2(e1, n1)
        EDGE_BODY2(e2, n2)
        EDGE_BODY2(e3, n3)
        EDGE_BODY2(e4, n4)
        EDGE_BODY2(e5, n5)
        EDGE_BODY2(e6, n6)
        EDGE_BODY2(e7, n7)

        cur = nxt;
        i += 8;
    }
    for (; i < cnt; i++) {
        int2 r0 = rbase[i];
        int e0 = __builtin_amdgcn_readfirstlane(r0.x);
        int n0 = __builtin_amdgcn_readfirstlane(r0.y);
        EDGE_BODY2(e0, n0)
    }

    const float SCALE = 0.1f;
    float* op = out + (size_t)wave * (16 * KDIM) + (size_t)(4 * h) * KDIM + k0;
    float2 r0 = make_float2(a0x * SCALE, a0y * SCALE);
    float2 r1 = make_float2(a1x * SCALE, a1y * SCALE);
    float2 r2 = make_float2(a2x * SCALE, a2y * SCALE);
    float2 r3 = make_float2(a3x * SCALE, a3y * SCALE);
    *(float2*)(op + 0 * KDIM) = r0;
    *(float2*)(op + 1 * KDIM) = r1;
    *(float2*)(op + 2 * KDIM) = r2;
    *(float2*)(op + 3 * KDIM) = r3;
}

extern "C" void kernel_launch(void* const* d_in, const int* in_sizes, int n_in,
                              void* d_out, int out_size, void* d_ws, size_t ws_size,
                              hipStream_t stream) {
    const float* sh        = (const float*)d_in[0];   // (E, 16)
    const float* rb        = (const float*)d_in[1];   // (E, 4, 32)
    const float* emb       = (const float*)d_in[2];   // (N, 32)
    const int*   centers   = (const int*)d_in[3];     // (E,)
    const int*   neighbors = (const int*)d_in[4];     // (E,)

    int E = in_sizes[3];
    int N = in_sizes[2] / KDIM;

    float* out = (float*)d_out;

    int2* recs   = (int2*)d_ws;               // N*CAP records (25.6 MB)
    int*  cursor = (int*)(recs + (size_t)N * CAP);  // N

    hipMemsetAsync(cursor, 0, (size_t)N * sizeof(int), stream);

    scatter_slots_kernel<<<(E + 255) / 256, 256, 0, stream>>>(centers, neighbors,
                                                              cursor, recs, E);

    int blocks = (N * 64 + 255) / 256;        // one wave per atom
    imp_main_kernel<<<blocks, 256, 0, stream>>>(sh, rb, emb, recs, cursor, out, N);
}

// Round 7
// 547.240 us; speedup vs baseline: 1.0241x; 1.0241x over previous
//
#include <hip/hip_runtime.h>

#define KDIM 32
#define CAP 160   // slot capacity per atom; counts ~ Poisson(32), P(>=160) ~ 0

// ---------------- slotted CSR build: one memset + one scatter pass ----------
// recs[c*CAP + pos] = (edge_id, neighbor_id), pos = atomicAdd(cursor[c])
__global__ void scatter_slots_kernel(const int* __restrict__ centers,
                                     const int* __restrict__ neighbors,
                                     int* __restrict__ cursor,
                                     int2* __restrict__ recs, int n) {
    int i = blockIdx.x * blockDim.x + threadIdx.x;
    if (i < n) {
        int c  = centers[i];
        int nn = neighbors[i];
        int pos = atomicAdd(&cursor[c], 1);
        if (pos < CAP) recs[(size_t)c * CAP + pos] = make_int2(i, nn);
    }
}

// ---------------- main: one wave per atom, 8-edge batched rec fetch --------
// lane = h*32 + k ; lane owns output rows mm = 8h + j (j=0..7), column k.
// l(mm): mm0->l0, mm1..3->l1, mm4..8->l2, mm9..15->l3
//  h=0: j=0 -> t0 ; j=1..3 -> t1 ; j=4..7 -> t2
//  h=1: j=0 -> t2 ; j=1..7 -> t3
// sh needed by lane: sh[e*16 + 8h + j], j=0..7 -> two float4 loads, no selects.
// recs fetched 8-at-a-time via one lane-distributed load (lane l&7 reads
// recs[i+(l&7)]), extracted with v_readlane; next batch prefetched one
// iteration ahead so rec latency hides under gathers+FMAs.
// [R5 lesson: 2-wide lane remap (4 wide gathers/edge) was neutral-to-worse;
//  main is bound by random-512B gather efficiency, not vmem instruction count]

#define EDGE_BODY(EB, RP, SHP)                                            \
    {                                                                     \
        float t0 = RP[0 * KDIM + k] * EB;                                 \
        float t1 = RP[1 * KDIM + k] * EB;                                 \
        float t2 = RP[2 * KDIM + k] * EB;                                 \
        float t3 = RP[3 * KDIM + k] * EB;                                 \
        float4 sA = SHP[0];                                               \
        float4 sB = SHP[1];                                               \
        float c0 = hb ? t2 : t0;                                          \
        float c1 = hb ? t3 : t1;                                          \
        float c2 = hb ? t3 : t2;                                          \
        a0 += sA.x * c0;                                                  \
        a1 += sA.y * c1;                                                  \
        a2 += sA.z * c1;                                                  \
        a3 += sA.w * c1;                                                  \
        a4 += sB.x * c2;                                                  \
        a5 += sB.y * c2;                                                  \
        a6 += sB.z * c2;                                                  \
        a7 += sB.w * c2;                                                  \
    }

// gather + FMA for 4 edges whose (e,n) are already in SGPRs
#define GROUP4(E0, N0, E1, N1, E2, N2, E3, N3)                            \
    {                                                                     \
        float eb0 = emb[(size_t)(N0) * KDIM + k];                         \
        float eb1 = emb[(size_t)(N1) * KDIM + k];                         \
        float eb2 = emb[(size_t)(N2) * KDIM + k];                         \
        float eb3 = emb[(size_t)(N3) * KDIM + k];                         \
        const float* rp0 = rb + (size_t)(E0) * (4 * KDIM);                \
        const float* rp1 = rb + (size_t)(E1) * (4 * KDIM);                \
        const float* rp2 = rb + (size_t)(E2) * (4 * KDIM);                \
        const float* rp3 = rb + (size_t)(E3) * (4 * KDIM);                \
        const float4* sp0 = (const float4*)(sh + (size_t)(E0) * 16 + 8 * h); \
        const float4* sp1 = (const float4*)(sh + (size_t)(E1) * 16 + 8 * h); \
        const float4* sp2 = (const float4*)(sh + (size_t)(E2) * 16 + 8 * h); \
        const float4* sp3 = (const float4*)(sh + (size_t)(E3) * 16 + 8 * h); \
        EDGE_BODY(eb0, rp0, sp0)                                          \
        EDGE_BODY(eb1, rp1, sp1)                                          \
        EDGE_BODY(eb2, rp2, sp2)                                          \
        EDGE_BODY(eb3, rp3, sp3)                                          \
    }

#define RL(x, j) __builtin_amdgcn_readlane((x), (j))

__global__ __launch_bounds__(256) void imp_main_kernel(
    const float* __restrict__ sh, const float* __restrict__ rb,
    const float* __restrict__ emb, const int2* __restrict__ recs,
    const int* __restrict__ cursor, float* __restrict__ out, int n_atoms) {
    int wave = (blockIdx.x * blockDim.x + threadIdx.x) >> 6;
    int lane = threadIdx.x & 63;
    if (wave >= n_atoms) return;
    int k = lane & 31;
    int h = lane >> 5;
    bool hb = (h != 0);

    int cnt = cursor[wave];
    if (cnt > CAP) cnt = CAP;
    const int2* rbase = recs + (size_t)wave * CAP;

    float a0 = 0.f, a1 = 0.f, a2 = 0.f, a3 = 0.f;
    float a4 = 0.f, a5 = 0.f, a6 = 0.f, a7 = 0.f;

    int l8 = lane & 7;
    int i = 0;
    int2 cur = make_int2(0, 0);
    if (cnt >= 8) cur = rbase[l8];          // preload batch 0
    while (i + 8 <= cnt) {
        int2 nxt = cur;
        if (i + 16 <= cnt) nxt = rbase[i + 8 + l8];  // prefetch next batch

        int e0 = RL(cur.x, 0), n0 = RL(cur.y, 0);
        int e1 = RL(cur.x, 1), n1 = RL(cur.y, 1);
        int e2 = RL(cur.x, 2), n2 = RL(cur.y, 2);
        int e3 = RL(cur.x, 3), n3 = RL(cur.y, 3);
        int e4 = RL(cur.x, 4), n4 = RL(cur.y, 4);
        int e5 = RL(cur.x, 5), n5 = RL(cur.y, 5);
        int e6 = RL(cur.x, 6), n6 = RL(cur.y, 6);
        int e7 = RL(cur.x, 7), n7 = RL(cur.y, 7);

        GROUP4(e0, n0, e1, n1, e2, n2, e3, n3)
        GROUP4(e4, n4, e5, n5, e6, n6, e7, n7)

        cur = nxt;
        i += 8;
    }
    for (; i < cnt; i++) {
        int2 r0 = rbase[i];
        int e0 = __builtin_amdgcn_readfirstlane(r0.x);
        int n0 = __builtin_amdgcn_readfirstlane(r0.y);
        float eb0 = emb[(size_t)n0 * KDIM + k];
        const float* rp0 = rb + (size_t)e0 * (4 * KDIM);
        const float4* sp0 = (const float4*)(sh + (size_t)e0 * 16 + 8 * h);
        EDGE_BODY(eb0, rp0, sp0)
    }

    const float SCALE = 0.1f;
    float* op = out + (size_t)wave * (16 * KDIM) + (size_t)(8 * h) * KDIM + k;
    op[0 * KDIM] = a0 * SCALE;
    op[1 * KDIM] = a1 * SCALE;
    op[2 * KDIM] = a2 * SCALE;
    op[3 * KDIM] = a3 * SCALE;
    op[4 * KDIM] = a4 * SCALE;
    op[5 * KDIM] = a5 * SCALE;
    op[6 * KDIM] = a6 * SCALE;
    op[7 * KDIM] = a7 * SCALE;
}

extern "C" void kernel_launch(void* const* d_in, const int* in_sizes, int n_in,
                              void* d_out, int out_size, void* d_ws, size_t ws_size,
                              hipStream_t stream) {
    const float* sh        = (const float*)d_in[0];   // (E, 16)
    const float* rb        = (const float*)d_in[1];   // (E, 4, 32)
    const float* emb       = (const float*)d_in[2];   // (N, 32)
    const int*   centers   = (const int*)d_in[3];     // (E,)
    const int*   neighbors = (const int*)d_in[4];     // (E,)

    int E = in_sizes[3];
    int N = in_sizes[2] / KDIM;

    float* out = (float*)d_out;

    int2* recs   = (int2*)d_ws;               // N*CAP records (25.6 MB)
    int*  cursor = (int*)(recs + (size_t)N * CAP);  // N

    hipMemsetAsync(cursor, 0, (size_t)N * sizeof(int), stream);

    scatter_slots_kernel<<<(E + 255) / 256, 256, 0, stream>>>(centers, neighbors,
                                                              cursor, recs, E);

    int blocks = (N * 64 + 255) / 256;        // one wave per atom
    imp_main_kernel<<<blocks, 256, 0, stream>>>(sh, rb, emb, recs, cursor, out, N);
}